// Round 12
// baseline (836.385 us; speedup 1.0000x reference)
//
#include <hip/hip_runtime.h>
#include <cstdint>
#include <cstddef>

// GRU cell as two f16 MFMA GEMMs.
// Round 12: A-operand DIRECT global->register (LDS bypassed for A; LDS was the
// measured bottleneck at ~78% BW). B stays in ring-3 LDS via global_load_lds.
// Per phase: [vmcnt(5); BAR; ds_read bF(t); loadA(t+1)->regs; dmaB(t+2);
//            lgkm(0); prio1; 16 MFMA(aCur,bF); prio0]   (single barrier/phase)
// M = 131072 rows, A=128, H=512, K = 640.
// prep_all: x->x16, h->h16, weights -> f16 panels B1 [1024][640], B2 [512][640]
// K1: [x16|h16] @ B1^T -> z (f16 ws / fp32 d_out), rh = sigmoid(ar)*h16 (f16 ws)
// K2: [x16|rh ] @ B2^T -> h_new = h16 + z*(tanh(ah)-h16)

#define M_ROWS 131072
#define A_DIM 128
#define H_DIM 512
#define K_TOT 640
#define BK 32
#define NSTEPS 20
#define XSTEPS 4
#define BM 256
#define BN 128
#define BSLOT 8192     // B ring slot: 128 rows x 32 k x f16 = 8KB; 3 slots = 24KB

typedef _Float16 f16;
typedef _Float16 f16x8 __attribute__((ext_vector_type(8)));
typedef float f32x4 __attribute__((ext_vector_type(4)));

#define AS1 __attribute__((address_space(1)))
#define AS3 __attribute__((address_space(3)))

__device__ __forceinline__ void gload_lds16(const void* g, void* l) {
  __builtin_amdgcn_global_load_lds((const AS1 unsigned int*)g,
                                   (AS3 unsigned int*)l, 16, 0, 0);
}

__device__ __forceinline__ float sigmoid_f(float v) {
  return __builtin_amdgcn_rcpf(1.0f + __expf(-v));
}
__device__ __forceinline__ float tanh_f(float v) {
  float c = fminf(fmaxf(v, -15.0f), 15.0f);
  float e = __expf(2.0f * c);
  return (e - 1.0f) * __builtin_amdgcn_rcpf(e + 1.0f);
}

// ---------------- fused prep: x/h cvt + weight transpose in ONE launch ----------------
#define NX8 (M_ROWS * A_DIM / 8)            // 2,097,152 8-elem chunks
#define NH8 (M_ROWS * H_DIM / 8)            // 8,388,608
#define NW  (1024 * K_TOT + H_DIM * K_TOT)  // 983,040 elements

__global__ void prep_all(const float* __restrict__ x, const float* __restrict__ h,
                         const float* __restrict__ wz, const float* __restrict__ uz,
                         const float* __restrict__ wr, const float* __restrict__ ur,
                         const float* __restrict__ wh, const float* __restrict__ uh,
                         f16* __restrict__ x16, f16* __restrict__ h16,
                         f16* __restrict__ B1, f16* __restrict__ B2) {
  const long total = (long)NX8 + NH8 + NW;
  long i = (long)blockIdx.x * blockDim.x + threadIdx.x;
  const long stride = (long)gridDim.x * blockDim.x;
  for (; i < total; i += stride) {
    if (i < NX8 + NH8) {
      const float* src; f16* dst; long e;
      if (i < NX8) { src = x; dst = x16; e = i * 8; }
      else         { src = h; dst = h16; e = (i - NX8) * 8; }
      float4 v0 = *(const float4*)(src + e);
      float4 v1 = *(const float4*)(src + e + 4);
      f16x8 o;
      o[0] = (_Float16)v0.x; o[1] = (_Float16)v0.y; o[2] = (_Float16)v0.z; o[3] = (_Float16)v0.w;
      o[4] = (_Float16)v1.x; o[5] = (_Float16)v1.y; o[6] = (_Float16)v1.z; o[7] = (_Float16)v1.w;
      *(f16x8*)(dst + e) = o;
    } else {
      int idx = (int)(i - NX8 - NH8);
      const int n1 = 1024 * K_TOT;
      if (idx < n1) {
        int n = idx / K_TOT, k = idx % K_TOT;
        float v;
        if (k < A_DIM) v = (n < H_DIM) ? wz[k * H_DIM + n] : wr[k * H_DIM + (n - H_DIM)];
        else           v = (n < H_DIM) ? uz[(k - A_DIM) * H_DIM + n] : ur[(k - A_DIM) * H_DIM + (n - H_DIM)];
        B1[idx] = (f16)v;
      } else {
        int idx2 = idx - n1;
        int n = idx2 / K_TOT, k = idx2 % K_TOT;
        float v = (k < A_DIM) ? wh[k * H_DIM + n] : uh[(k - A_DIM) * H_DIM + n];
        B2[idx2] = (f16)v;
      }
    }
  }
}

// (kept for the low-workspace fallback path)
__global__ void build_wcat(const float* __restrict__ wz, const float* __restrict__ uz,
                           const float* __restrict__ wr, const float* __restrict__ ur,
                           const float* __restrict__ wh, const float* __restrict__ uh,
                           f16* __restrict__ B1, f16* __restrict__ B2) {
  int idx = blockIdx.x * blockDim.x + threadIdx.x;
  const int n1 = 1024 * K_TOT;
  if (idx < n1) {
    int n = idx / K_TOT, k = idx % K_TOT;
    float v;
    if (k < A_DIM) v = (n < H_DIM) ? wz[k * H_DIM + n] : wr[k * H_DIM + (n - H_DIM)];
    else           v = (n < H_DIM) ? uz[(k - A_DIM) * H_DIM + n] : ur[(k - A_DIM) * H_DIM + (n - H_DIM)];
    B1[idx] = (f16)v;
  } else {
    int idx2 = idx - n1;
    if (idx2 < H_DIM * K_TOT) {
      int n = idx2 / K_TOT, k = idx2 % K_TOT;
      float v = (k < A_DIM) ? wh[k * H_DIM + n] : uh[(k - A_DIM) * H_DIM + n];
      B2[idx2] = (f16)v;
    }
  }
}

// ---------------- A-direct GEMM (B via ring-3 LDS) + staged epilogue ----------------
// 8 waves (4m x 2n), wave tile 64x64, 16 MFMA/phase, BK=32.
// LDS: B ring 3 x 8KB = 24KB; epilogue staging reuses 64KB (2 blocks/CU).
// A frags: per-lane 16B contiguous global loads (each mi-group = 16 rows x one
// aligned 64B line) with single-phase register prefetch (aX/aY named sets).
// vmcnt audit (phase issue order: ds_read bF; loadA(t+1); dmaB(t+2)):
//   ops newer than B(t) at phase-t top = A(t)x4 + B(t+1)x1 = 5 -> vmcnt(5)
//   (t=0: prologue [A(0),B(0),B(1)] -> 1; t=19: no B(20) -> 4).
// A-regs are compiler-tracked loads (it inserts its own precise vmcnt).
// B-slot WAR with single barrier: readers of B(t-1) retired their ds_reads via
// lgkm(0) before MFMA(t-1), before reaching the phase-t barrier; dmaB(t+2)
// issues after that barrier -> race-free.
template <int MODE>  // 1: N=1024 (z|r), A=[x16|h16].  2: N=512, A=[x16|rh].
__global__ __launch_bounds__(512, 4)
void gru_gemm16a(const f16* __restrict__ A0, const f16* __restrict__ A1,
                 const f16* __restrict__ h16, const f16* __restrict__ Bt,
                 const float* __restrict__ bias0, const float* __restrict__ bias1,
                 float* __restrict__ out, f16* __restrict__ rh_out,
                 f16* __restrict__ z16) {
  constexpr int NBLK = (MODE == 1) ? 8 : 4;
  __shared__ __align__(16) char smem[65536];   // B ring 24KB; epilogue 64KB

  // XCD-bijective swizzle (grid multiple of 8)
  const int per = gridDim.x >> 3;
  const int b = blockIdx.x;
  const int tile = (b & 7) * per + (b >> 3);
  const int nb = tile & (NBLK - 1);
  const int mb = tile / NBLK;
  const int m0 = mb * BM;
  const int n0 = nb * BN;

  const int tid = threadIdx.x;
  const int lane = tid & 63;
  const int wid = tid >> 6;          // 0..7
  const int wm = wid >> 1;           // 0..3 (64-row strip)
  const int wn = wid & 1;            // 0..1 (64-col strip)
  const int r16 = lane & 15;
  const int kh = lane >> 4;

  f32x4 acc[4][4];
#pragma unroll
  for (int i = 0; i < 4; ++i)
#pragma unroll
    for (int j = 0; j < 4; ++j) acc[i][j] = (f32x4){0.f, 0.f, 0.f, 0.f};

  auto dma_B = [&](int t, int slot) {   // 128x32 f16, 1 gload_lds16/thread
    char* Bw = smem + slot * BSLOT;
    const int s = tid;                      // 0..511
    const int row = s >> 2;                 // 0..127
    const int c = (s & 3) ^ ((row >> 1) & 3);
    const f16* g = Bt + (size_t)(n0 + row) * K_TOT + t * BK + c * 8;
    gload_lds16(g, Bw + wid * 1024);
  };

  // B fragment LDS byte offsets (XOR swizzle folded in), slot-relative
  int boff[4];
#pragma unroll
  for (int ni = 0; ni < 4; ++ni) {
    const int rb = wn * 64 + ni * 16 + r16;
    boff[ni] = rb * 64 + ((kh ^ ((rb >> 1) & 3)) << 4);
  }

  const int arow = m0 + wm * 64 + r16;
  auto loadA = [&](int t, f16x8* aF) {   // 4 x 16B coalesced global loads
    const f16* src = (t < XSTEPS) ? A0 : A1;
    const int ld = (t < XSTEPS) ? A_DIM : H_DIM;
    const int colb = ((t < XSTEPS) ? t * BK : t * BK - A_DIM) + kh * 8;
#pragma unroll
    for (int mi = 0; mi < 4; ++mi)
      aF[mi] = *(const f16x8*)(src + (size_t)(arow + mi * 16) * ld + colb);
  };

  f16x8 aX[4], aY[4];   // named register sets (no dynamic indexing)

  auto phase = [&](int t, const f16x8* aC, f16x8* aN) {
    if (t == 0)              asm volatile("s_waitcnt vmcnt(1)" ::: "memory");
    else if (t < NSTEPS - 1) asm volatile("s_waitcnt vmcnt(5)" ::: "memory");
    else                     asm volatile("s_waitcnt vmcnt(4)" ::: "memory");
    __builtin_amdgcn_s_barrier();       // B(t) visible to all waves
    asm volatile("" ::: "memory");
    const char* Bl = smem + (t % 3) * BSLOT;
    f16x8 bF[4];
#pragma unroll
    for (int ni = 0; ni < 4; ++ni) bF[ni] = *(const f16x8*)(Bl + boff[ni]);
    if (t + 1 < NSTEPS) loadA(t + 1, aN);            // overlaps MFMA below
    if (t + 2 < NSTEPS) dma_B(t + 2, (t + 2) % 3);   // slot (t-1)%3, WAR-safe
    asm volatile("s_waitcnt lgkmcnt(0)" ::: "memory");  // bF resident
    __builtin_amdgcn_sched_barrier(0);
    __builtin_amdgcn_s_setprio(1);
#pragma unroll
    for (int mi = 0; mi < 4; ++mi)
#pragma unroll
      for (int ni = 0; ni < 4; ++ni)
        acc[mi][ni] = __builtin_amdgcn_mfma_f32_16x16x32_f16(aC[mi], bF[ni], acc[mi][ni], 0, 0, 0);
    __builtin_amdgcn_s_setprio(0);
    asm volatile("" ::: "memory");
  };

  // prologue: A(0)->aX, B(0)->slot0, B(1)->slot1
  loadA(0, aX);
  dma_B(0, 0);
  dma_B(1, 1);

  for (int t = 0; t < NSTEPS; t += 2) {   // NSTEPS even
    phase(t, aX, aY);
    phase(t + 1, aY, aX);
  }

  // ---- staged epilogue (r7/r8/r11-verified) ----
  const bool zhalf = (MODE == 1) && (n0 < H_DIM);   // block-uniform
  float b4[4];
#pragma unroll
  for (int ni = 0; ni < 4; ++ni) {
    const int n_g = n0 + wn * 64 + ni * 16 + r16;
    b4[ni] = (MODE == 2) ? bias0[n_g] : (zhalf ? bias0[n_g] : bias1[n_g - H_DIM]);
  }
  __syncthreads();   // all waves done with B ring
  char* ep = smem;
#pragma unroll
  for (int mi = 0; mi < 4; ++mi) {
#pragma unroll
    for (int ni = 0; ni < 4; ++ni) {
      const int C = wn * 64 + ni * 16 + r16;
      const int sw = ((C >> 3) ^ (kh << 1)) << 4;
      const int cb = (C & 7) * 2;
#pragma unroll
      for (int r = 0; r < 4; ++r) {
        const int R = wm * 64 + mi * 16 + kh * 4 + r;
        const float v = acc[mi][ni][r] + b4[ni];
        const float a = (MODE == 2) ? tanh_f(v) : sigmoid_f(v);
        *(f16*)(ep + R * 256 + sw + cb) = (f16)a;
      }
    }
  }
  __syncthreads();

#pragma unroll
  for (int j = 0; j < 8; ++j) {
    const int sIdx = j * 512 + tid;
    const int R = sIdx >> 4;             // 0..255
    const int ss = sIdx & 15;            // global slot within row
    const int sr = ss ^ (((R >> 2) & 3) << 1);
    const f16x8 tv = *(const f16x8*)(ep + R * 256 + sr * 16);
    const size_t m_g = (size_t)(m0 + R);
    if (MODE == 1) {
      if (zhalf) {
        const size_t off = m_g * H_DIM + n0 + ss * 8;
        if (z16) {
          *(f16x8*)(z16 + off) = tv;
        } else {
          float4 o0, o1;
          o0.x = (float)tv[0]; o0.y = (float)tv[1]; o0.z = (float)tv[2]; o0.w = (float)tv[3];
          o1.x = (float)tv[4]; o1.y = (float)tv[5]; o1.z = (float)tv[6]; o1.w = (float)tv[7];
          *(float4*)(out + off) = o0;
          *(float4*)(out + off + 4) = o1;
        }
      } else {
        const size_t off = m_g * H_DIM + (n0 - H_DIM) + ss * 8;
        const f16x8 hv = *(const f16x8*)(h16 + off);
        f16x8 rv;
#pragma unroll
        for (int e = 0; e < 8; ++e) rv[e] = (f16)((float)tv[e] * (float)hv[e]);
        *(f16x8*)(rh_out + off) = rv;
      }
    } else {
      const size_t off = m_g * H_DIM + n0 + ss * 8;
      const f16x8 hv = *(const f16x8*)(h16 + off);
      float zz[8];
      if (z16) {
        const f16x8 zv = *(const f16x8*)(z16 + off);
#pragma unroll
        for (int e = 0; e < 8; ++e) zz[e] = (float)zv[e];
      } else {
        const float4 z0 = *(const float4*)(out + off);
        const float4 z1 = *(const float4*)(out + off + 4);
        zz[0] = z0.x; zz[1] = z0.y; zz[2] = z0.z; zz[3] = z0.w;
        zz[4] = z1.x; zz[5] = z1.y; zz[6] = z1.z; zz[7] = z1.w;
      }
      float4 o0, o1;
      float oo[8];
#pragma unroll
      for (int e = 0; e < 8; ++e) {
        const float hh = (float)hv[e];
        oo[e] = fmaf(zz[e], (float)tv[e] - hh, hh);
      }
      o0.x = oo[0]; o0.y = oo[1]; o0.z = oo[2]; o0.w = oo[3];
      o1.x = oo[4]; o1.y = oo[5]; o1.z = oo[6]; o1.w = oo[7];
      *(float4*)(out + off) = o0;
      *(float4*)(out + off + 4) = o1;
    }
  }
}

// ---------------- fallback GEMM (round-2 proven, needs only ~136MB ws) ----------------
template <int MODE>
__global__ __launch_bounds__(256, 2)
void gru_gemm_fb(const float* __restrict__ x, const float* __restrict__ h,
                 const f16* __restrict__ Bt, const f16* __restrict__ rh_in,
                 const float* __restrict__ bias0, const float* __restrict__ bias1,
                 float* __restrict__ out, f16* __restrict__ rh_out) {
  constexpr int NBLK = (MODE == 1) ? 8 : 4;
  __shared__ __align__(16) char smem[2 * 16384];

  const int per = gridDim.x >> 3;
  const int b = blockIdx.x;
  const int tile = (b & 7) * per + (b >> 3);
  const int nb = tile & (NBLK - 1);
  const int mb = tile / NBLK;
  const int m0 = mb * 128;
  const int n0 = nb * 128;

  const int tid = threadIdx.x;
  const int lane = tid & 63;
  const int wid = tid >> 6;
  const int wm = wid >> 1;
  const int wn = wid & 1;
  const int r16 = lane & 15;
  const int kh = lane >> 4;

  f32x4 acc[4][4];
#pragma unroll
  for (int i = 0; i < 4; ++i)
#pragma unroll
    for (int j = 0; j < 4; ++j) acc[i][j] = (f32x4){0.f, 0.f, 0.f, 0.f};

  float4 fa0, fa1, fa2, fa3;

  auto dma_B = [&](int t, int buf) {
    char* Bw = smem + buf * 16384 + 8192;
#pragma unroll
    for (int i = 0; i < 2; ++i) {
      const int chunk = wid * 2 + i;
      const int s = chunk * 64 + lane;
      const int row = s >> 2, c = s & 3;
      const f16* g = Bt + (size_t)(n0 + row) * K_TOT + t * 32 + c * 8;
      gload_lds16(g, Bw + chunk * 1024);
    }
  };
  auto dma_A_rh = [&](int t, int buf) {
    char* Aw = smem + buf * 16384;
    const int col = t * 32 - A_DIM;
#pragma unroll
    for (int i = 0; i < 2; ++i) {
      const int chunk = wid * 2 + i;
      const int s = chunk * 64 + lane;
      const int row = s >> 2, c = s & 3;
      const f16* g = rh_in + (size_t)(m0 + row) * H_DIM + col + c * 8;
      gload_lds16(g, Aw + chunk * 1024);
    }
  };
  auto load_A_regs = [&](int t) {
    const float* src = (t < XSTEPS) ? x : h;
    const int ld = (t < XSTEPS) ? A_DIM : H_DIM;
    const int col = (t < XSTEPS) ? t * 32 : t * 32 - A_DIM;
    {
      const int s = tid, row = s >> 2, c = s & 3;
      const float* g = src + (size_t)(m0 + row) * ld + col + c * 8;
      fa0 = *(const float4*)g;
      fa1 = *(const float4*)(g + 4);
    }
    {
      const int s = tid + 256, row = s >> 2, c = s & 3;
      const float* g = src + (size_t)(m0 + row) * ld + col + c * 8;
      fa2 = *(const float4*)g;
      fa3 = *(const float4*)(g + 4);
    }
  };
  auto write_A = [&](int buf) {
    char* Aw = smem + buf * 16384;
    f16x8 v;
    v[0] = (_Float16)fa0.x; v[1] = (_Float16)fa0.y; v[2] = (_Float16)fa0.z; v[3] = (_Float16)fa0.w;
    v[4] = (_Float16)fa1.x; v[5] = (_Float16)fa1.y; v[6] = (_Float16)fa1.z; v[7] = (_Float16)fa1.w;
    *(f16x8*)(Aw + tid * 16) = v;
    f16x8 w;
    w[0] = (_Float16)fa2.x; w[1] = (_Float16)fa2.y; w[2] = (_Float16)fa2.z; w[3] = (_Float16)fa2.w;
    w[4] = (_Float16)fa3.x; w[5] = (_Float16)fa3.y; w[6] = (_Float16)fa3.z; w[7] = (_Float16)fa3.w;
    *(f16x8*)(Aw + (tid + 256) * 16) = w;
  };

  dma_B(0, 0);
  load_A_regs(0);
  write_A(0);
  __syncthreads();

  int cur = 0;
  for (int t = 0; t < NSTEPS; ++t) {
    const int nxt = t + 1;
    const bool have = nxt < NSTEPS;
    const bool nxt_dma_A = (MODE == 2) && (nxt >= XSTEPS);
    if (have) {
      dma_B(nxt, cur ^ 1);
      if (nxt_dma_A) dma_A_rh(nxt, cur ^ 1);
      else load_A_regs(nxt);
    }
    const char* Al = smem + cur * 16384;
    const char* Bl = Al + 8192;
    f16x8 aF[4], bF[4];
#pragma unroll
    for (int mi = 0; mi < 4; ++mi)
      aF[mi] = *(const f16x8*)(Al + (wm * 64 + mi * 16 + r16) * 64 + kh * 16);
#pragma unroll
    for (int ni = 0; ni < 4; ++ni)
      bF[ni] = *(const f16x8*)(Bl + (wn * 64 + ni * 16 + r16) * 64 + kh * 16);
#pragma unroll
    for (int mi = 0; mi < 4; ++mi)
#pragma unroll
      for (int ni = 0; ni < 4; ++ni)
        acc[mi][ni] = __builtin_amdgcn_mfma_f32_16x16x32_f16(aF[mi], bF[ni], acc[mi][ni], 0, 0, 0);
    if (have && !nxt_dma_A) write_A(cur ^ 1);
    __syncthreads();
    cur ^= 1;
  }

#pragma unroll
  for (int mi = 0; mi < 4; ++mi) {
#pragma unroll
    for (int ni = 0; ni < 4; ++ni) {
      const int n_g = n0 + wn * 64 + ni * 16 + r16;
#pragma unroll
      for (int r = 0; r < 4; ++r) {
        const int m_g = m0 + wm * 64 + mi * 16 + kh * 4 + r;
        float v = acc[mi][ni][r];
        if (MODE == 1) {
          if (n_g < H_DIM) {
            out[(size_t)m_g * H_DIM + n_g] = sigmoid_f(v + bias0[n_g]);
          } else {
            const int j = n_g - H_DIM;
            const size_t off = (size_t)m_g * H_DIM + j;
            float rv = sigmoid_f(v + bias1[j]);
            rh_out[off] = (f16)(rv * h[off]);
          }
        } else {
          const size_t off = (size_t)m_g * H_DIM + n_g;
          float th = tanh_f(v + bias0[n_g]);
          float zv = out[off];
          float hv = h[off];
          out[off] = fmaf(zv, th - hv, hv);
        }
      }
    }
  }
}

extern "C" void kernel_launch(void* const* d_in, const int* in_sizes, int n_in,
                              void* d_out, int out_size, void* d_ws, size_t ws_size,
                              hipStream_t stream) {
  const float* x  = (const float*)d_in[0];
  const float* h  = (const float*)d_in[1];
  const float* wz = (const float*)d_in[2];
  const float* uz = (const float*)d_in[3];
  const float* bz = (const float*)d_in[4];
  const float* wr = (const float*)d_in[5];
  const float* ur = (const float*)d_in[6];
  const float* br = (const float*)d_in[7];
  const float* wh = (const float*)d_in[8];
  const float* uh = (const float*)d_in[9];
  const float* bh = (const float*)d_in[10];
  float* out = (float*)d_out;

  char* ws = (char*)d_ws;
  const size_t B1_B  = (size_t)1024 * K_TOT * 2;     //   1,310,720
  const size_t B2_B  = (size_t)H_DIM * K_TOT * 2;    //     655,360
  const size_t RH_B  = (size_t)M_ROWS * H_DIM * 2;   // 134,217,728
  const size_t X16_B = (size_t)M_ROWS * A_DIM * 2;   //  33,554,432
  const size_t H16_B = RH_B;
  const size_t Z16_B = RH_B;

  f16* B1 = (f16*)ws;
  f16* B2 = (f16*)(ws + B1_B);
  f16* rh = (f16*)(ws + B1_B + B2_B);

  const size_t need_base = B1_B + B2_B + RH_B + X16_B + H16_B;  // ~304 MB
  const int wtot = NW;

  if (ws_size >= need_base) {
    f16* x16 = (f16*)(ws + B1_B + B2_B + RH_B);
    f16* h16 = (f16*)(ws + B1_B + B2_B + RH_B + X16_B);
    f16* z16 = (ws_size >= need_base + Z16_B) ? (f16*)(ws + need_base) : nullptr;

    prep_all<<<dim3(2048), dim3(256), 0, stream>>>(
        x, h, wz, uz, wr, ur, wh, uh, x16, h16, B1, B2);
    gru_gemm16a<1><<<dim3((M_ROWS / BM) * 8), dim3(512), 0, stream>>>(
        x16, h16, h16, B1, bz, br, out, rh, z16);
    gru_gemm16a<2><<<dim3((M_ROWS / BM) * 4), dim3(512), 0, stream>>>(
        x16, rh, h16, B2, bh, nullptr, out, nullptr, z16);
  } else {
    build_wcat<<<dim3((wtot + 255) / 256), dim3(256), 0, stream>>>(wz, uz, wr, ur, wh, uh, B1, B2);
    gru_gemm_fb<1><<<dim3((M_ROWS / 128) * 8), dim3(256), 0, stream>>>(x, h, B1, nullptr, bz, br, out, rh);
    gru_gemm_fb<2><<<dim3((M_ROWS / 128) * 4), dim3(256), 0, stream>>>(x, h, B2, rh, bh, nullptr, out, rh);
  }
}

// Round 13
// 608.633 us; speedup vs baseline: 1.3742x; 1.3742x over previous
//
#include <hip/hip_runtime.h>
#include <cstdint>
#include <cstddef>

// GRU cell as two all-f16 MFMA GEMMs.
// Round 13: r11 (best: ring-3 counted-vmcnt loop, staged epilogue, fused prep)
// + K2 in-loop L2 prefetch of epilogue operands (z16,h16) via global_load_lds
// into a garbage LDS slot: warms L2 under the LDS-bound K-loop so the
// epilogue's 268MB of reads become L2 hits instead of post-loop HBM stalls.
// M = 131072 rows, A=128, H=512, K = 640.
// prep_all: x->x16, h->h16, weights -> f16 panels B1 [1024][640], B2 [512][640]
// K1: [x16|h16] @ B1^T -> z (f16 ws / fp32 d_out), rh = sigmoid(ar)*h16 (f16 ws)
// K2: [x16|rh ] @ B2^T -> h_new = h16 + z*(tanh(ah)-h16)

#define M_ROWS 131072
#define A_DIM 128
#define H_DIM 512
#define K_TOT 640
#define BK 32
#define NSTEPS 20
#define XSTEPS 4
#define BM 256
#define BN 128
#define SLOT_B 24576   // A 16KB + B 8KB per ring slot; 3 slots = 72KB (+4KB pf garbage)

typedef _Float16 f16;
typedef _Float16 f16x8 __attribute__((ext_vector_type(8)));
typedef float f32x4 __attribute__((ext_vector_type(4)));

#define AS1 __attribute__((address_space(1)))
#define AS3 __attribute__((address_space(3)))

__device__ __forceinline__ void gload_lds16(const void* g, void* l) {
  __builtin_amdgcn_global_load_lds((const AS1 unsigned int*)g,
                                   (AS3 unsigned int*)l, 16, 0, 0);
}

__device__ __forceinline__ float sigmoid_f(float v) {
  return __builtin_amdgcn_rcpf(1.0f + __expf(-v));
}
__device__ __forceinline__ float tanh_f(float v) {
  float c = fminf(fmaxf(v, -15.0f), 15.0f);
  float e = __expf(2.0f * c);
  return (e - 1.0f) * __builtin_amdgcn_rcpf(e + 1.0f);
}

// ---------------- fused prep: x/h cvt + weight transpose in ONE launch ----------------
#define NX8 (M_ROWS * A_DIM / 8)            // 2,097,152 8-elem chunks
#define NH8 (M_ROWS * H_DIM / 8)            // 8,388,608
#define NW  (1024 * K_TOT + H_DIM * K_TOT)  // 983,040 elements

__global__ void prep_all(const float* __restrict__ x, const float* __restrict__ h,
                         const float* __restrict__ wz, const float* __restrict__ uz,
                         const float* __restrict__ wr, const float* __restrict__ ur,
                         const float* __restrict__ wh, const float* __restrict__ uh,
                         f16* __restrict__ x16, f16* __restrict__ h16,
                         f16* __restrict__ B1, f16* __restrict__ B2) {
  const long total = (long)NX8 + NH8 + NW;
  long i = (long)blockIdx.x * blockDim.x + threadIdx.x;
  const long stride = (long)gridDim.x * blockDim.x;
  for (; i < total; i += stride) {
    if (i < NX8 + NH8) {
      const float* src; f16* dst; long e;
      if (i < NX8) { src = x; dst = x16; e = i * 8; }
      else         { src = h; dst = h16; e = (i - NX8) * 8; }
      float4 v0 = *(const float4*)(src + e);
      float4 v1 = *(const float4*)(src + e + 4);
      f16x8 o;
      o[0] = (_Float16)v0.x; o[1] = (_Float16)v0.y; o[2] = (_Float16)v0.z; o[3] = (_Float16)v0.w;
      o[4] = (_Float16)v1.x; o[5] = (_Float16)v1.y; o[6] = (_Float16)v1.z; o[7] = (_Float16)v1.w;
      *(f16x8*)(dst + e) = o;
    } else {
      int idx = (int)(i - NX8 - NH8);
      const int n1 = 1024 * K_TOT;
      if (idx < n1) {
        int n = idx / K_TOT, k = idx % K_TOT;
        float v;
        if (k < A_DIM) v = (n < H_DIM) ? wz[k * H_DIM + n] : wr[k * H_DIM + (n - H_DIM)];
        else           v = (n < H_DIM) ? uz[(k - A_DIM) * H_DIM + n] : ur[(k - A_DIM) * H_DIM + (n - H_DIM)];
        B1[idx] = (f16)v;
      } else {
        int idx2 = idx - n1;
        int n = idx2 / K_TOT, k = idx2 % K_TOT;
        float v = (k < A_DIM) ? wh[k * H_DIM + n] : uh[(k - A_DIM) * H_DIM + n];
        B2[idx2] = (f16)v;
      }
    }
  }
}

// (kept for the low-workspace fallback path)
__global__ void build_wcat(const float* __restrict__ wz, const float* __restrict__ uz,
                           const float* __restrict__ wr, const float* __restrict__ ur,
                           const float* __restrict__ wh, const float* __restrict__ uh,
                           f16* __restrict__ B1, f16* __restrict__ B2) {
  int idx = blockIdx.x * blockDim.x + threadIdx.x;
  const int n1 = 1024 * K_TOT;
  if (idx < n1) {
    int n = idx / K_TOT, k = idx % K_TOT;
    float v;
    if (k < A_DIM) v = (n < H_DIM) ? wz[k * H_DIM + n] : wr[k * H_DIM + (n - H_DIM)];
    else           v = (n < H_DIM) ? uz[(k - A_DIM) * H_DIM + n] : ur[(k - A_DIM) * H_DIM + (n - H_DIM)];
    B1[idx] = (f16)v;
  } else {
    int idx2 = idx - n1;
    if (idx2 < H_DIM * K_TOT) {
      int n = idx2 / K_TOT, k = idx2 % K_TOT;
      float v = (k < A_DIM) ? wh[k * H_DIM + n] : uh[(k - A_DIM) * H_DIM + n];
      B2[idx2] = (f16)v;
    }
  }
}

// ---------------- ring-3 phase-disciplined GEMM + staged epilogue ----------------
// Loop structure r8/r11-verified; MODE2 adds 1 prefetch gload_lds/wave/phase
// (t=1..16) covering the block's z16+h16 tiles (16 x 8KB = 128KB exactly).
// vmcnt audit (order-robust): tile t's 3 DMAs always have >=4 younger vmem ops
// by phase t (3 DMA + 1 pf issued since), so vmcnt(4) at t in [2,17] forces
// tile t retired; t in {0,1,18}: 3; t=19: 0. MODE1 keeps r11's 3/0 schedule.
template <int MODE>  // 1: N=1024 (z|r), A=[x16|h16].  2: N=512, A=[x16|rh].
__global__ __launch_bounds__(512, 4)
void gru_gemm16e(const f16* __restrict__ A0, const f16* __restrict__ A1,
                 const f16* __restrict__ h16, const f16* __restrict__ Bt,
                 const float* __restrict__ bias0, const float* __restrict__ bias1,
                 float* __restrict__ out, f16* __restrict__ rh_out,
                 f16* __restrict__ z16) {
  constexpr int NBLK = (MODE == 1) ? 8 : 4;
  __shared__ __align__(16) char smem[3 * SLOT_B + 4096];  // 76KB (4KB pf garbage)

  // XCD-bijective swizzle (grid multiple of 8)
  const int per = gridDim.x >> 3;
  const int b = blockIdx.x;
  const int tile = (b & 7) * per + (b >> 3);
  const int nb = tile & (NBLK - 1);
  const int mb = tile / NBLK;
  const int m0 = mb * BM;
  const int n0 = nb * BN;

  const int tid = threadIdx.x;
  const int lane = tid & 63;
  const int wid = tid >> 6;          // 0..7
  const int wm = wid >> 1;           // 0..3 (64-row strip)
  const int wn = wid & 1;            // 0..1 (64-col strip)
  const int r16 = lane & 15;
  const int kh = lane >> 4;

  f32x4 acc[4][4];
#pragma unroll
  for (int i = 0; i < 4; ++i)
#pragma unroll
    for (int j = 0; j < 4; ++j) acc[i][j] = (f32x4){0.f, 0.f, 0.f, 0.f};

  auto dma_A = [&](int t, int slot) {   // 256x32 f16, 2 loads/thread
    char* Aw = smem + slot * SLOT_B;
    const f16* src = (t < XSTEPS) ? A0 : A1;
    const int ld = (t < XSTEPS) ? A_DIM : H_DIM;
    const int colb = (t < XSTEPS) ? t * BK : t * BK - A_DIM;
#pragma unroll
    for (int j = 0; j < 2; ++j) {
      const int s = j * 512 + tid;          // 16B-chunk index 0..1023
      const int row = s >> 2;               // 0..255
      const int c = (s & 3) ^ ((row >> 1) & 3);
      const f16* g = src + (size_t)(m0 + row) * ld + colb + c * 8;
      gload_lds16(g, Aw + j * 8192 + wid * 1024);
    }
  };
  auto dma_B = [&](int t, int slot) {   // 128x32 f16, 1 load/thread
    char* Bw = smem + slot * SLOT_B + 16384;
    const int s = tid;                      // 0..511
    const int row = s >> 2;                 // 0..127
    const int c = (s & 3) ^ ((row >> 1) & 3);
    const f16* g = Bt + (size_t)(n0 + row) * K_TOT + t * BK + c * 8;
    gload_lds16(g, Bw + wid * 1024);
  };

  // MODE2 epilogue-operand L2 prefetch (z16 then h16; 16 phases x 512 chunks
  // = 8192 = 2 arrays x 256 rows x 16 chunks). Dest is garbage LDS.
  const f16* pfA = (MODE == 2) ? (z16 ? z16 : h16) : nullptr;
  auto pf = [&](int t) {
    const int id = (t - 1) * 512 + tid;     // 0..8191
    const f16* arr = (id < 4096) ? pfA : h16;
    const int cid = id & 4095;
    const int row = cid >> 4;               // 0..255
    const int cc = cid & 15;                // 16B chunk in 128-col strip
    const f16* g = arr + (size_t)(m0 + row) * H_DIM + n0 + cc * 8;
    gload_lds16(g, smem + 3 * SLOT_B + (wid & 3) * 1024);
  };

  // prologue: tiles 0,1 in flight (6 loads/thread)
  dma_A(0, 0); dma_B(0, 0);
  dma_A(1, 1); dma_B(1, 1);

  // loop-invariant fragment LDS byte offsets (XOR swizzle folded in)
  int aoff[4], boff[4];
#pragma unroll
  for (int mi = 0; mi < 4; ++mi) {
    const int ra = wm * 64 + mi * 16 + r16;
    aoff[mi] = ra * 64 + ((kh ^ ((ra >> 1) & 3)) << 4);
  }
#pragma unroll
  for (int ni = 0; ni < 4; ++ni) {
    const int rb = wn * 64 + ni * 16 + r16;
    boff[ni] = 16384 + rb * 64 + ((kh ^ ((rb >> 1) & 3)) << 4);
  }

  for (int t = 0; t < NSTEPS; ++t) {
    if (MODE == 2) {
      if (t >= 2 && t <= 17)       asm volatile("s_waitcnt vmcnt(4)" ::: "memory");
      else if (t < NSTEPS - 1)     asm volatile("s_waitcnt vmcnt(3)" ::: "memory");
      else                         asm volatile("s_waitcnt vmcnt(0)" ::: "memory");
    } else {
      if (t < NSTEPS - 1)          asm volatile("s_waitcnt vmcnt(3)" ::: "memory");
      else                         asm volatile("s_waitcnt vmcnt(0)" ::: "memory");
    }
    __builtin_amdgcn_s_barrier();
    asm volatile("" ::: "memory");

    const char* Sl = smem + (t % 3) * SLOT_B;
    f16x8 aF[4], bF[4];
#pragma unroll
    for (int mi = 0; mi < 4; ++mi) aF[mi] = *(const f16x8*)(Sl + aoff[mi]);
#pragma unroll
    for (int ni = 0; ni < 4; ++ni) bF[ni] = *(const f16x8*)(Sl + boff[ni]);

    if (t + 2 < NSTEPS) {   // -> slot (t+2)%3 == (t-1)%3, fenced by prev closing BAR
      dma_A(t + 2, (t + 2) % 3);
      dma_B(t + 2, (t + 2) % 3);
    }
    if (MODE == 2 && t >= 1 && t <= 16) pf(t);

    asm volatile("s_waitcnt lgkmcnt(0)" ::: "memory");  // frags resident
    __builtin_amdgcn_s_setprio(1);
#pragma unroll
    for (int mi = 0; mi < 4; ++mi)
#pragma unroll
      for (int ni = 0; ni < 4; ++ni)
        acc[mi][ni] = __builtin_amdgcn_mfma_f32_16x16x32_f16(aF[mi], bF[ni], acc[mi][ni], 0, 0, 0);
    __builtin_amdgcn_s_setprio(0);
    asm volatile("" ::: "memory");
    __builtin_amdgcn_s_barrier();   // closing barrier: all waves' reads of t done
    asm volatile("" ::: "memory");
  }

  // ---- staged epilogue (r7/r8/r11-verified) ----
  const bool zhalf = (MODE == 1) && (n0 < H_DIM);   // block-uniform
  float b4[4];
#pragma unroll
  for (int ni = 0; ni < 4; ++ni) {
    const int n_g = n0 + wn * 64 + ni * 16 + r16;
    b4[ni] = (MODE == 2) ? bias0[n_g] : (zhalf ? bias0[n_g] : bias1[n_g - H_DIM]);
  }
  __syncthreads();   // all waves done with ring slots (drains all vmem incl. pf)
  char* ep = smem;
#pragma unroll
  for (int mi = 0; mi < 4; ++mi) {
#pragma unroll
    for (int ni = 0; ni < 4; ++ni) {
      const int C = wn * 64 + ni * 16 + r16;
      const int sw = ((C >> 3) ^ (kh << 1)) << 4;
      const int cb = (C & 7) * 2;
#pragma unroll
      for (int r = 0; r < 4; ++r) {
        const int R = wm * 64 + mi * 16 + kh * 4 + r;
        const float v = acc[mi][ni][r] + b4[ni];
        const float a = (MODE == 2) ? tanh_f(v) : sigmoid_f(v);
        *(f16*)(ep + R * 256 + sw + cb) = (f16)a;
      }
    }
  }
  __syncthreads();

#pragma unroll
  for (int j = 0; j < 8; ++j) {
    const int sIdx = j * 512 + tid;
    const int R = sIdx >> 4;             // 0..255
    const int ss = sIdx & 15;            // global slot within row
    const int sr = ss ^ (((R >> 2) & 3) << 1);
    const f16x8 tv = *(const f16x8*)(ep + R * 256 + sr * 16);
    const size_t m_g = (size_t)(m0 + R);
    if (MODE == 1) {
      if (zhalf) {
        const size_t off = m_g * H_DIM + n0 + ss * 8;
        if (z16) {
          *(f16x8*)(z16 + off) = tv;
        } else {
          float4 o0, o1;
          o0.x = (float)tv[0]; o0.y = (float)tv[1]; o0.z = (float)tv[2]; o0.w = (float)tv[3];
          o1.x = (float)tv[4]; o1.y = (float)tv[5]; o1.z = (float)tv[6]; o1.w = (float)tv[7];
          *(float4*)(out + off) = o0;
          *(float4*)(out + off + 4) = o1;
        }
      } else {
        const size_t off = m_g * H_DIM + (n0 - H_DIM) + ss * 8;
        const f16x8 hv = *(const f16x8*)(h16 + off);
        f16x8 rv;
#pragma unroll
        for (int e = 0; e < 8; ++e) rv[e] = (f16)((float)tv[e] * (float)hv[e]);
        *(f16x8*)(rh_out + off) = rv;
      }
    } else {
      const size_t off = m_g * H_DIM + n0 + ss * 8;
      const f16x8 hv = *(const f16x8*)(h16 + off);
      float zz[8];
      if (z16) {
        const f16x8 zv = *(const f16x8*)(z16 + off);
#pragma unroll
        for (int e = 0; e < 8; ++e) zz[e] = (float)zv[e];
      } else {
        const float4 z0 = *(const float4*)(out + off);
        const float4 z1 = *(const float4*)(out + off + 4);
        zz[0] = z0.x; zz[1] = z0.y; zz[2] = z0.z; zz[3] = z0.w;
        zz[4] = z1.x; zz[5] = z1.y; zz[6] = z1.z; zz[7] = z1.w;
      }
      float4 o0, o1;
      float oo[8];
#pragma unroll
      for (int e = 0; e < 8; ++e) {
        const float hh = (float)hv[e];
        oo[e] = fmaf(zz[e], (float)tv[e] - hh, hh);
      }
      o0.x = oo[0]; o0.y = oo[1]; o0.z = oo[2]; o0.w = oo[3];
      o1.x = oo[4]; o1.y = oo[5]; o1.z = oo[6]; o1.w = oo[7];
      *(float4*)(out + off) = o0;
      *(float4*)(out + off + 4) = o1;
    }
  }
}

// ---------------- fallback GEMM (round-2 proven, needs only ~136MB ws) ----------------
template <int MODE>
__global__ __launch_bounds__(256, 2)
void gru_gemm_fb(const float* __restrict__ x, const float* __restrict__ h,
                 const f16* __restrict__ Bt, const f16* __restrict__ rh_in,
                 const float* __restrict__ bias0, const float* __restrict__ bias1,
                 float* __restrict__ out, f16* __restrict__ rh_out) {
  constexpr int NBLK = (MODE == 1) ? 8 : 4;
  __shared__ __align__(16) char smem[2 * 16384];

  const int per = gridDim.x >> 3;
  const int b = blockIdx.x;
  const int tile = (b & 7) * per + (b >> 3);
  const int nb = tile & (NBLK - 1);
  const int mb = tile / NBLK;
  const int m0 = mb * 128;
  const int n0 = nb * 128;

  const int tid = threadIdx.x;
  const int lane = tid & 63;
  const int wid = tid >> 6;
  const int wm = wid >> 1;
  const int wn = wid & 1;
  const int r16 = lane & 15;
  const int kh = lane >> 4;

  f32x4 acc[4][4];
#pragma unroll
  for (int i = 0; i < 4; ++i)
#pragma unroll
    for (int j = 0; j < 4; ++j) acc[i][j] = (f32x4){0.f, 0.f, 0.f, 0.f};

  float4 fa0, fa1, fa2, fa3;

  auto dma_B = [&](int t, int buf) {
    char* Bw = smem + buf * 16384 + 8192;
#pragma unroll
    for (int i = 0; i < 2; ++i) {
      const int chunk = wid * 2 + i;
      const int s = chunk * 64 + lane;
      const int row = s >> 2, c = s & 3;
      const f16* g = Bt + (size_t)(n0 + row) * K_TOT + t * 32 + c * 8;
      gload_lds16(g, Bw + chunk * 1024);
    }
  };
  auto dma_A_rh = [&](int t, int buf) {
    char* Aw = smem + buf * 16384;
    const int col = t * 32 - A_DIM;
#pragma unroll
    for (int i = 0; i < 2; ++i) {
      const int chunk = wid * 2 + i;
      const int s = chunk * 64 + lane;
      const int row = s >> 2, c = s & 3;
      const f16* g = rh_in + (size_t)(m0 + row) * H_DIM + col + c * 8;
      gload_lds16(g, Aw + chunk * 1024);
    }
  };
  auto load_A_regs = [&](int t) {
    const float* src = (t < XSTEPS) ? x : h;
    const int ld = (t < XSTEPS) ? A_DIM : H_DIM;
    const int col = (t < XSTEPS) ? t * 32 : t * 32 - A_DIM;
    {
      const int s = tid, row = s >> 2, c = s & 3;
      const float* g = src + (size_t)(m0 + row) * ld + col + c * 8;
      fa0 = *(const float4*)g;
      fa1 = *(const float4*)(g + 4);
    }
    {
      const int s = tid + 256, row = s >> 2, c = s & 3;
      const float* g = src + (size_t)(m0 + row) * ld + col + c * 8;
      fa2 = *(const float4*)g;
      fa3 = *(const float4*)(g + 4);
    }
  };
  auto write_A = [&](int buf) {
    char* Aw = smem + buf * 16384;
    f16x8 v;
    v[0] = (_Float16)fa0.x; v[1] = (_Float16)fa0.y; v[2] = (_Float16)fa0.z; v[3] = (_Float16)fa0.w;
    v[4] = (_Float16)fa1.x; v[5] = (_Float16)fa1.y; v[6] = (_Float16)fa1.z; v[7] = (_Float16)fa1.w;
    *(f16x8*)(Aw + tid * 16) = v;
    f16x8 w;
    w[0] = (_Float16)fa2.x; w[1] = (_Float16)fa2.y; w[2] = (_Float16)fa2.z; w[3] = (_Float16)fa2.w;
    w[4] = (_Float16)fa3.x; w[5] = (_Float16)fa3.y; w[6] = (_Float16)fa3.z; w[7] = (_Float16)fa3.w;
    *(f16x8*)(Aw + (tid + 256) * 16) = w;
  };

  dma_B(0, 0);
  load_A_regs(0);
  write_A(0);
  __syncthreads();

  int cur = 0;
  for (int t = 0; t < NSTEPS; ++t) {
    const int nxt = t + 1;
    const bool have = nxt < NSTEPS;
    const bool nxt_dma_A = (MODE == 2) && (nxt >= XSTEPS);
    if (have) {
      dma_B(nxt, cur ^ 1);
      if (nxt_dma_A) dma_A_rh(nxt, cur ^ 1);
      else load_A_regs(nxt);
    }
    const char* Al = smem + cur * 16384;
    const char* Bl = Al + 8192;
    f16x8 aF[4], bF[4];
#pragma unroll
    for (int mi = 0; mi < 4; ++mi)
      aF[mi] = *(const f16x8*)(Al + (wm * 64 + mi * 16 + r16) * 64 + kh * 16);
#pragma unroll
    for (int ni = 0; ni < 4; ++ni)
      bF[ni] = *(const f16x8*)(Bl + (wn * 64 + ni * 16 + r16) * 64 + kh * 16);
#pragma unroll
    for (int mi = 0; mi < 4; ++mi)
#pragma unroll
      for (int ni = 0; ni < 4; ++ni)
        acc[mi][ni] = __builtin_amdgcn_mfma_f32_16x16x32_f16(aF[mi], bF[ni], acc[mi][ni], 0, 0, 0);
    if (have && !nxt_dma_A) write_A(cur ^ 1);
    __syncthreads();
    cur ^= 1;
  }

#pragma unroll
  for (int mi = 0; mi < 4; ++mi) {
#pragma unroll
    for (int ni = 0; ni < 4; ++ni) {
      const int n_g = n0 + wn * 64 + ni * 16 + r16;
#pragma unroll
      for (int r = 0; r < 4; ++r) {
        const int m_g = m0 + wm * 64 + mi * 16 + kh * 4 + r;
        float v = acc[mi][ni][r];
        if (MODE == 1) {
          if (n_g < H_DIM) {
            out[(size_t)m_g * H_DIM + n_g] = sigmoid_f(v + bias0[n_g]);
          } else {
            const int j = n_g - H_DIM;
            const size_t off = (size_t)m_g * H_DIM + j;
            float rv = sigmoid_f(v + bias1[j]);
            rh_out[off] = (f16)(rv * h[off]);
          }
        } else {
          const size_t off = (size_t)m_g * H_DIM + n_g;
          float th = tanh_f(v + bias0[n_g]);
          float zv = out[off];
          float hv = h[off];
          out[off] = fmaf(zv, th - hv, hv);
        }
      }
    }
  }
}

extern "C" void kernel_launch(void* const* d_in, const int* in_sizes, int n_in,
                              void* d_out, int out_size, void* d_ws, size_t ws_size,
                              hipStream_t stream) {
  const float* x  = (const float*)d_in[0];
  const float* h  = (const float*)d_in[1];
  const float* wz = (const float*)d_in[2];
  const float* uz = (const float*)d_in[3];
  const float* bz = (const float*)d_in[4];
  const float* wr = (const float*)d_in[5];
  const float* ur = (const float*)d_in[6];
  const float* br = (const float*)d_in[7];
  const float* wh = (const float*)d_in[8];
  const float* uh = (const float*)d_in[9];
  const float* bh = (const float*)d_in[10];
  float* out = (float*)d_out;

  char* ws = (char*)d_ws;
  const size_t B1_B  = (size_t)1024 * K_TOT * 2;     //   1,310,720
  const size_t B2_B  = (size_t)H_DIM * K_TOT * 2;    //     655,360
  const size_t RH_B  = (size_t)M_ROWS * H_DIM * 2;   // 134,217,728
  const size_t X16_B = (size_t)M_ROWS * A_DIM * 2;   //  33,554,432
  const size_t H16_B = RH_B;
  const size_t Z16_B = RH_B;

  f16* B1 = (f16*)ws;
  f16* B2 = (f16*)(ws + B1_B);
  f16* rh = (f16*)(ws + B1_B + B2_B);

  const size_t need_base = B1_B + B2_B + RH_B + X16_B + H16_B;  // ~304 MB
  const int wtot = NW;

  if (ws_size >= need_base) {
    f16* x16 = (f16*)(ws + B1_B + B2_B + RH_B);
    f16* h16 = (f16*)(ws + B1_B + B2_B + RH_B + X16_B);
    f16* z16 = (ws_size >= need_base + Z16_B) ? (f16*)(ws + need_base) : nullptr;

    prep_all<<<dim3(2048), dim3(256), 0, stream>>>(
        x, h, wz, uz, wr, ur, wh, uh, x16, h16, B1, B2);
    gru_gemm16e<1><<<dim3((M_ROWS / BM) * 8), dim3(512), 0, stream>>>(
        x16, h16, h16, B1, bz, br, out, rh, z16);
    gru_gemm16e<2><<<dim3((M_ROWS / BM) * 4), dim3(512), 0, stream>>>(
        x16, rh, h16, B2, bh, nullptr, out, nullptr, z16);
  } else {
    build_wcat<<<dim3((wtot + 255) / 256), dim3(256), 0, stream>>>(wz, uz, wr, ur, wh, uh, B1, B2);
    gru_gemm_fb<1><<<dim3((M_ROWS / 128) * 8), dim3(256), 0, stream>>>(x, h, B1, nullptr, bz, br, out, rh);
    gru_gemm_fb<2><<<dim3((M_ROWS / 128) * 4), dim3(256), 0, stream>>>(x, h, B2, rh, bh, nullptr, out, rh);
  }
}

// Round 14
// 563.146 us; speedup vs baseline: 1.4852x; 1.0808x over previous
//
#include <hip/hip_runtime.h>
#include <cstdint>
#include <cstddef>

// GRU cell as two all-f16 MFMA GEMMs.
// FINAL (r11 verified best, 563.9 us): ring-3 counted-vmcnt loop, phase-
// disciplined (double barrier + setprio), BM=256/BN=128, 8 waves, staged
// coalesced epilogue, fused single prep launch, XCD-bijective block swizzle.
// M = 131072 rows, A=128, H=512, K = 640.
// prep_all: x->x16, h->h16, weights -> f16 panels B1 [1024][640], B2 [512][640]
// K1: [x16|h16] @ B1^T -> z (f16 ws / fp32 d_out), rh = sigmoid(ar)*h16 (f16 ws)
// K2: [x16|rh ] @ B2^T -> h_new = h16 + z*(tanh(ah)-h16)

#define M_ROWS 131072
#define A_DIM 128
#define H_DIM 512
#define K_TOT 640
#define BK 32
#define NSTEPS 20
#define XSTEPS 4
#define BM 256
#define BN 128
#define SLOT_B 24576   // A 16KB + B 8KB per ring slot; 3 slots = 72KB

typedef _Float16 f16;
typedef _Float16 f16x8 __attribute__((ext_vector_type(8)));
typedef float f32x4 __attribute__((ext_vector_type(4)));

#define AS1 __attribute__((address_space(1)))
#define AS3 __attribute__((address_space(3)))

__device__ __forceinline__ void gload_lds16(const void* g, void* l) {
  __builtin_amdgcn_global_load_lds((const AS1 unsigned int*)g,
                                   (AS3 unsigned int*)l, 16, 0, 0);
}

__device__ __forceinline__ float sigmoid_f(float v) {
  return __builtin_amdgcn_rcpf(1.0f + __expf(-v));
}
__device__ __forceinline__ float tanh_f(float v) {
  float c = fminf(fmaxf(v, -15.0f), 15.0f);
  float e = __expf(2.0f * c);
  return (e - 1.0f) * __builtin_amdgcn_rcpf(e + 1.0f);
}

// ---------------- fused prep: x/h cvt + weight transpose in ONE launch ----------------
#define NX8 (M_ROWS * A_DIM / 8)            // 2,097,152 8-elem chunks
#define NH8 (M_ROWS * H_DIM / 8)            // 8,388,608
#define NW  (1024 * K_TOT + H_DIM * K_TOT)  // 983,040 elements

__global__ void prep_all(const float* __restrict__ x, const float* __restrict__ h,
                         const float* __restrict__ wz, const float* __restrict__ uz,
                         const float* __restrict__ wr, const float* __restrict__ ur,
                         const float* __restrict__ wh, const float* __restrict__ uh,
                         f16* __restrict__ x16, f16* __restrict__ h16,
                         f16* __restrict__ B1, f16* __restrict__ B2) {
  const long total = (long)NX8 + NH8 + NW;
  long i = (long)blockIdx.x * blockDim.x + threadIdx.x;
  const long stride = (long)gridDim.x * blockDim.x;
  for (; i < total; i += stride) {
    if (i < NX8 + NH8) {
      const float* src; f16* dst; long e;
      if (i < NX8) { src = x; dst = x16; e = i * 8; }
      else         { src = h; dst = h16; e = (i - NX8) * 8; }
      float4 v0 = *(const float4*)(src + e);
      float4 v1 = *(const float4*)(src + e + 4);
      f16x8 o;
      o[0] = (_Float16)v0.x; o[1] = (_Float16)v0.y; o[2] = (_Float16)v0.z; o[3] = (_Float16)v0.w;
      o[4] = (_Float16)v1.x; o[5] = (_Float16)v1.y; o[6] = (_Float16)v1.z; o[7] = (_Float16)v1.w;
      *(f16x8*)(dst + e) = o;
    } else {
      int idx = (int)(i - NX8 - NH8);
      const int n1 = 1024 * K_TOT;
      if (idx < n1) {
        int n = idx / K_TOT, k = idx % K_TOT;
        float v;
        if (k < A_DIM) v = (n < H_DIM) ? wz[k * H_DIM + n] : wr[k * H_DIM + (n - H_DIM)];
        else           v = (n < H_DIM) ? uz[(k - A_DIM) * H_DIM + n] : ur[(k - A_DIM) * H_DIM + (n - H_DIM)];
        B1[idx] = (f16)v;
      } else {
        int idx2 = idx - n1;
        int n = idx2 / K_TOT, k = idx2 % K_TOT;
        float v = (k < A_DIM) ? wh[k * H_DIM + n] : uh[(k - A_DIM) * H_DIM + n];
        B2[idx2] = (f16)v;
      }
    }
  }
}

// (kept for the low-workspace fallback path)
__global__ void build_wcat(const float* __restrict__ wz, const float* __restrict__ uz,
                           const float* __restrict__ wr, const float* __restrict__ ur,
                           const float* __restrict__ wh, const float* __restrict__ uh,
                           f16* __restrict__ B1, f16* __restrict__ B2) {
  int idx = blockIdx.x * blockDim.x + threadIdx.x;
  const int n1 = 1024 * K_TOT;
  if (idx < n1) {
    int n = idx / K_TOT, k = idx % K_TOT;
    float v;
    if (k < A_DIM) v = (n < H_DIM) ? wz[k * H_DIM + n] : wr[k * H_DIM + (n - H_DIM)];
    else           v = (n < H_DIM) ? uz[(k - A_DIM) * H_DIM + n] : ur[(k - A_DIM) * H_DIM + (n - H_DIM)];
    B1[idx] = (f16)v;
  } else {
    int idx2 = idx - n1;
    if (idx2 < H_DIM * K_TOT) {
      int n = idx2 / K_TOT, k = idx2 % K_TOT;
      float v = (k < A_DIM) ? wh[k * H_DIM + n] : uh[(k - A_DIM) * H_DIM + n];
      B2[idx2] = (f16)v;
    }
  }
}

// ---------------- ring-3 phase-disciplined GEMM + staged epilogue (r8/r11-verified) ----------------
// 8 waves (4m x 2n), wave tile 64x64, 16 MFMA/phase, BK=32.
// LDS: 3 ring slots x 24KB = 72KB (2 blocks/CU); epilogue reuses first 64KB.
// Phase(t): vmcnt(3) [tile t retired, t+1 in flight]; BAR; ds_read frags(t);
// issue DMA(t+2) -> slot (t-1)%3 [reads of t-1 fenced by prev phase's
// lgkm(0)+closing BAR]; lgkm(0); setprio(1); 16 MFMA; setprio(0); BAR.
template <int MODE>  // 1: N=1024 (z|r), A=[x16|h16].  2: N=512, A=[x16|rh].
__global__ __launch_bounds__(512, 4)
void gru_gemm16p(const f16* __restrict__ A0, const f16* __restrict__ A1,
                 const f16* __restrict__ h16, const f16* __restrict__ Bt,
                 const float* __restrict__ bias0, const float* __restrict__ bias1,
                 float* __restrict__ out, f16* __restrict__ rh_out,
                 f16* __restrict__ z16) {
  constexpr int NBLK = (MODE == 1) ? 8 : 4;
  __shared__ __align__(16) char smem[3 * SLOT_B];

  // XCD-bijective swizzle (grid multiple of 8)
  const int per = gridDim.x >> 3;
  const int b = blockIdx.x;
  const int tile = (b & 7) * per + (b >> 3);
  const int nb = tile & (NBLK - 1);
  const int mb = tile / NBLK;
  const int m0 = mb * BM;
  const int n0 = nb * BN;

  const int tid = threadIdx.x;
  const int lane = tid & 63;
  const int wid = tid >> 6;          // 0..7
  const int wm = wid >> 1;           // 0..3 (64-row strip)
  const int wn = wid & 1;            // 0..1 (64-col strip)
  const int r16 = lane & 15;
  const int kh = lane >> 4;

  f32x4 acc[4][4];
#pragma unroll
  for (int i = 0; i < 4; ++i)
#pragma unroll
    for (int j = 0; j < 4; ++j) acc[i][j] = (f32x4){0.f, 0.f, 0.f, 0.f};

  auto dma_A = [&](int t, int slot) {   // 256x32 f16, 2 loads/thread
    char* Aw = smem + slot * SLOT_B;
    const f16* src = (t < XSTEPS) ? A0 : A1;
    const int ld = (t < XSTEPS) ? A_DIM : H_DIM;
    const int colb = (t < XSTEPS) ? t * BK : t * BK - A_DIM;
#pragma unroll
    for (int j = 0; j < 2; ++j) {
      const int s = j * 512 + tid;          // 16B-chunk index 0..1023
      const int row = s >> 2;               // 0..255
      const int c = (s & 3) ^ ((row >> 1) & 3);
      const f16* g = src + (size_t)(m0 + row) * ld + colb + c * 8;
      gload_lds16(g, Aw + j * 8192 + wid * 1024);
    }
  };
  auto dma_B = [&](int t, int slot) {   // 128x32 f16, 1 load/thread
    char* Bw = smem + slot * SLOT_B + 16384;
    const int s = tid;                      // 0..511
    const int row = s >> 2;                 // 0..127
    const int c = (s & 3) ^ ((row >> 1) & 3);
    const f16* g = Bt + (size_t)(n0 + row) * K_TOT + t * BK + c * 8;
    gload_lds16(g, Bw + wid * 1024);
  };

  // prologue: tiles 0,1 in flight (6 loads/thread)
  dma_A(0, 0); dma_B(0, 0);
  dma_A(1, 1); dma_B(1, 1);

  // loop-invariant fragment LDS byte offsets (XOR swizzle folded in)
  int aoff[4], boff[4];
#pragma unroll
  for (int mi = 0; mi < 4; ++mi) {
    const int ra = wm * 64 + mi * 16 + r16;
    aoff[mi] = ra * 64 + ((kh ^ ((ra >> 1) & 3)) << 4);
  }
#pragma unroll
  for (int ni = 0; ni < 4; ++ni) {
    const int rb = wn * 64 + ni * 16 + r16;
    boff[ni] = 16384 + rb * 64 + ((kh ^ ((rb >> 1) & 3)) << 4);
  }

  for (int t = 0; t < NSTEPS; ++t) {
    if (t < NSTEPS - 1) asm volatile("s_waitcnt vmcnt(3)" ::: "memory");
    else                asm volatile("s_waitcnt vmcnt(0)" ::: "memory");
    __builtin_amdgcn_s_barrier();
    asm volatile("" ::: "memory");

    const char* Sl = smem + (t % 3) * SLOT_B;
    f16x8 aF[4], bF[4];
#pragma unroll
    for (int mi = 0; mi < 4; ++mi) aF[mi] = *(const f16x8*)(Sl + aoff[mi]);
#pragma unroll
    for (int ni = 0; ni < 4; ++ni) bF[ni] = *(const f16x8*)(Sl + boff[ni]);

    if (t + 2 < NSTEPS) {   // -> slot (t+2)%3 == (t-1)%3, fenced by prev closing BAR
      dma_A(t + 2, (t + 2) % 3);
      dma_B(t + 2, (t + 2) % 3);
    }

    asm volatile("s_waitcnt lgkmcnt(0)" ::: "memory");  // frags resident
    __builtin_amdgcn_s_setprio(1);
#pragma unroll
    for (int mi = 0; mi < 4; ++mi)
#pragma unroll
      for (int ni = 0; ni < 4; ++ni)
        acc[mi][ni] = __builtin_amdgcn_mfma_f32_16x16x32_f16(aF[mi], bF[ni], acc[mi][ni], 0, 0, 0);
    __builtin_amdgcn_s_setprio(0);
    asm volatile("" ::: "memory");
    __builtin_amdgcn_s_barrier();   // closing barrier: all waves' reads of t done
    asm volatile("" ::: "memory");
  }

  // ---- staged epilogue (r7/r8/r11-verified) ----
  const bool zhalf = (MODE == 1) && (n0 < H_DIM);   // block-uniform
  float b4[4];
#pragma unroll
  for (int ni = 0; ni < 4; ++ni) {
    const int n_g = n0 + wn * 64 + ni * 16 + r16;
    b4[ni] = (MODE == 2) ? bias0[n_g] : (zhalf ? bias0[n_g] : bias1[n_g - H_DIM]);
  }
  __syncthreads();   // all waves done with ring slots
  char* ep = smem;
#pragma unroll
  for (int mi = 0; mi < 4; ++mi) {
#pragma unroll
    for (int ni = 0; ni < 4; ++ni) {
      const int C = wn * 64 + ni * 16 + r16;
      const int sw = ((C >> 3) ^ (kh << 1)) << 4;
      const int cb = (C & 7) * 2;
#pragma unroll
      for (int r = 0; r < 4; ++r) {
        const int R = wm * 64 + mi * 16 + kh * 4 + r;
        const float v = acc[mi][ni][r] + b4[ni];
        const float a = (MODE == 2) ? tanh_f(v) : sigmoid_f(v);
        *(f16*)(ep + R * 256 + sw + cb) = (f16)a;
      }
    }
  }
  __syncthreads();

#pragma unroll
  for (int j = 0; j < 8; ++j) {
    const int sIdx = j * 512 + tid;
    const int R = sIdx >> 4;             // 0..255
    const int ss = sIdx & 15;            // global slot within row
    const int sr = ss ^ (((R >> 2) & 3) << 1);
    const f16x8 tv = *(const f16x8*)(ep + R * 256 + sr * 16);
    const size_t m_g = (size_t)(m0 + R);
    if (MODE == 1) {
      if (zhalf) {
        const size_t off = m_g * H_DIM + n0 + ss * 8;
        if (z16) {
          *(f16x8*)(z16 + off) = tv;
        } else {
          float4 o0, o1;
          o0.x = (float)tv[0]; o0.y = (float)tv[1]; o0.z = (float)tv[2]; o0.w = (float)tv[3];
          o1.x = (float)tv[4]; o1.y = (float)tv[5]; o1.z = (float)tv[6]; o1.w = (float)tv[7];
          *(float4*)(out + off) = o0;
          *(float4*)(out + off + 4) = o1;
        }
      } else {
        const size_t off = m_g * H_DIM + (n0 - H_DIM) + ss * 8;
        const f16x8 hv = *(const f16x8*)(h16 + off);
        f16x8 rv;
#pragma unroll
        for (int e = 0; e < 8; ++e) rv[e] = (f16)((float)tv[e] * (float)hv[e]);
        *(f16x8*)(rh_out + off) = rv;
      }
    } else {
      const size_t off = m_g * H_DIM + n0 + ss * 8;
      const f16x8 hv = *(const f16x8*)(h16 + off);
      float zz[8];
      if (z16) {
        const f16x8 zv = *(const f16x8*)(z16 + off);
#pragma unroll
        for (int e = 0; e < 8; ++e) zz[e] = (float)zv[e];
      } else {
        const float4 z0 = *(const float4*)(out + off);
        const float4 z1 = *(const float4*)(out + off + 4);
        zz[0] = z0.x; zz[1] = z0.y; zz[2] = z0.z; zz[3] = z0.w;
        zz[4] = z1.x; zz[5] = z1.y; zz[6] = z1.z; zz[7] = z1.w;
      }
      float4 o0, o1;
      float oo[8];
#pragma unroll
      for (int e = 0; e < 8; ++e) {
        const float hh = (float)hv[e];
        oo[e] = fmaf(zz[e], (float)tv[e] - hh, hh);
      }
      o0.x = oo[0]; o0.y = oo[1]; o0.z = oo[2]; o0.w = oo[3];
      o1.x = oo[4]; o1.y = oo[5]; o1.z = oo[6]; o1.w = oo[7];
      *(float4*)(out + off) = o0;
      *(float4*)(out + off + 4) = o1;
    }
  }
}

// ---------------- fallback GEMM (round-2 proven, needs only ~136MB ws) ----------------
template <int MODE>
__global__ __launch_bounds__(256, 2)
void gru_gemm_fb(const float* __restrict__ x, const float* __restrict__ h,
                 const f16* __restrict__ Bt, const f16* __restrict__ rh_in,
                 const float* __restrict__ bias0, const float* __restrict__ bias1,
                 float* __restrict__ out, f16* __restrict__ rh_out) {
  constexpr int NBLK = (MODE == 1) ? 8 : 4;
  __shared__ __align__(16) char smem[2 * 16384];

  const int per = gridDim.x >> 3;
  const int b = blockIdx.x;
  const int tile = (b & 7) * per + (b >> 3);
  const int nb = tile & (NBLK - 1);
  const int mb = tile / NBLK;
  const int m0 = mb * 128;
  const int n0 = nb * 128;

  const int tid = threadIdx.x;
  const int lane = tid & 63;
  const int wid = tid >> 6;
  const int wm = wid >> 1;
  const int wn = wid & 1;
  const int r16 = lane & 15;
  const int kh = lane >> 4;

  f32x4 acc[4][4];
#pragma unroll
  for (int i = 0; i < 4; ++i)
#pragma unroll
    for (int j = 0; j < 4; ++j) acc[i][j] = (f32x4){0.f, 0.f, 0.f, 0.f};

  float4 fa0, fa1, fa2, fa3;

  auto dma_B = [&](int t, int buf) {
    char* Bw = smem + buf * 16384 + 8192;
#pragma unroll
    for (int i = 0; i < 2; ++i) {
      const int chunk = wid * 2 + i;
      const int s = chunk * 64 + lane;
      const int row = s >> 2, c = s & 3;
      const f16* g = Bt + (size_t)(n0 + row) * K_TOT + t * 32 + c * 8;
      gload_lds16(g, Bw + chunk * 1024);
    }
  };
  auto dma_A_rh = [&](int t, int buf) {
    char* Aw = smem + buf * 16384;
    const int col = t * 32 - A_DIM;
#pragma unroll
    for (int i = 0; i < 2; ++i) {
      const int chunk = wid * 2 + i;
      const int s = chunk * 64 + lane;
      const int row = s >> 2, c = s & 3;
      const f16* g = rh_in + (size_t)(m0 + row) * H_DIM + col + c * 8;
      gload_lds16(g, Aw + chunk * 1024);
    }
  };
  auto load_A_regs = [&](int t) {
    const float* src = (t < XSTEPS) ? x : h;
    const int ld = (t < XSTEPS) ? A_DIM : H_DIM;
    const int col = (t < XSTEPS) ? t * 32 : t * 32 - A_DIM;
    {
      const int s = tid, row = s >> 2, c = s & 3;
      const float* g = src + (size_t)(m0 + row) * ld + col + c * 8;
      fa0 = *(const float4*)g;
      fa1 = *(const float4*)(g + 4);
    }
    {
      const int s = tid + 256, row = s >> 2, c = s & 3;
      const float* g = src + (size_t)(m0 + row) * ld + col + c * 8;
      fa2 = *(const float4*)g;
      fa3 = *(const float4*)(g + 4);
    }
  };
  auto write_A = [&](int buf) {
    char* Aw = smem + buf * 16384;
    f16x8 v;
    v[0] = (_Float16)fa0.x; v[1] = (_Float16)fa0.y; v[2] = (_Float16)fa0.z; v[3] = (_Float16)fa0.w;
    v[4] = (_Float16)fa1.x; v[5] = (_Float16)fa1.y; v[6] = (_Float16)fa1.z; v[7] = (_Float16)fa1.w;
    *(f16x8*)(Aw + tid * 16) = v;
    f16x8 w;
    w[0] = (_Float16)fa2.x; w[1] = (_Float16)fa2.y; w[2] = (_Float16)fa2.z; w[3] = (_Float16)fa2.w;
    w[4] = (_Float16)fa3.x; w[5] = (_Float16)fa3.y; w[6] = (_Float16)fa3.z; w[7] = (_Float16)fa3.w;
    *(f16x8*)(Aw + (tid + 256) * 16) = w;
  };

  dma_B(0, 0);
  load_A_regs(0);
  write_A(0);
  __syncthreads();

  int cur = 0;
  for (int t = 0; t < NSTEPS; ++t) {
    const int nxt = t + 1;
    const bool have = nxt < NSTEPS;
    const bool nxt_dma_A = (MODE == 2) && (nxt >= XSTEPS);
    if (have) {
      dma_B(nxt, cur ^ 1);
      if (nxt_dma_A) dma_A_rh(nxt, cur ^ 1);
      else load_A_regs(nxt);
    }
    const char* Al = smem + cur * 16384;
    const char* Bl = Al + 8192;
    f16x8 aF[4], bF[4];
#pragma unroll
    for (int mi = 0; mi < 4; ++mi)
      aF[mi] = *(const f16x8*)(Al + (wm * 64 + mi * 16 + r16) * 64 + kh * 16);
#pragma unroll
    for (int ni = 0; ni < 4; ++ni)
      bF[ni] = *(const f16x8*)(Bl + (wn * 64 + ni * 16 + r16) * 64 + kh * 16);
#pragma unroll
    for (int mi = 0; mi < 4; ++mi)
#pragma unroll
      for (int ni = 0; ni < 4; ++ni)
        acc[mi][ni] = __builtin_amdgcn_mfma_f32_16x16x32_f16(aF[mi], bF[ni], acc[mi][ni], 0, 0, 0);
    if (have && !nxt_dma_A) write_A(cur ^ 1);
    __syncthreads();
    cur ^= 1;
  }

#pragma unroll
  for (int mi = 0; mi < 4; ++mi) {
#pragma unroll
    for (int ni = 0; ni < 4; ++ni) {
      const int n_g = n0 + wn * 64 + ni * 16 + r16;
#pragma unroll
      for (int r = 0; r < 4; ++r) {
        const int m_g = m0 + wm * 64 + mi * 16 + kh * 4 + r;
        float v = acc[mi][ni][r];
        if (MODE == 1) {
          if (n_g < H_DIM) {
            out[(size_t)m_g * H_DIM + n_g] = sigmoid_f(v + bias0[n_g]);
          } else {
            const int j = n_g - H_DIM;
            const size_t off = (size_t)m_g * H_DIM + j;
            float rv = sigmoid_f(v + bias1[j]);
            rh_out[off] = (f16)(rv * h[off]);
          }
        } else {
          const size_t off = (size_t)m_g * H_DIM + n_g;
          float th = tanh_f(v + bias0[n_g]);
          float zv = out[off];
          float hv = h[off];
          out[off] = fmaf(zv, th - hv, hv);
        }
      }
    }
  }
}

extern "C" void kernel_launch(void* const* d_in, const int* in_sizes, int n_in,
                              void* d_out, int out_size, void* d_ws, size_t ws_size,
                              hipStream_t stream) {
  const float* x  = (const float*)d_in[0];
  const float* h  = (const float*)d_in[1];
  const float* wz = (const float*)d_in[2];
  const float* uz = (const float*)d_in[3];
  const float* bz = (const float*)d_in[4];
  const float* wr = (const float*)d_in[5];
  const float* ur = (const float*)d_in[6];
  const float* br = (const float*)d_in[7];
  const float* wh = (const float*)d_in[8];
  const float* uh = (const float*)d_in[9];
  const float* bh = (const float*)d_in[10];
  float* out = (float*)d_out;

  char* ws = (char*)d_ws;
  const size_t B1_B  = (size_t)1024 * K_TOT * 2;     //   1,310,720
  const size_t B2_B  = (size_t)H_DIM * K_TOT * 2;    //     655,360
  const size_t RH_B  = (size_t)M_ROWS * H_DIM * 2;   // 134,217,728
  const size_t X16_B = (size_t)M_ROWS * A_DIM * 2;   //  33,554,432
  const size_t H16_B = RH_B;
  const size_t Z16_B = RH_B;

  f16* B1 = (f16*)ws;
  f16* B2 = (f16*)(ws + B1_B);
  f16* rh = (f16*)(ws + B1_B + B2_B);

  const size_t need_base = B1_B + B2_B + RH_B + X16_B + H16_B;  // ~304 MB
  const int wtot = NW;

  if (ws_size >= need_base) {
    f16* x16 = (f16*)(ws + B1_B + B2_B + RH_B);
    f16* h16 = (f16*)(ws + B1_B + B2_B + RH_B + X16_B);
    f16* z16 = (ws_size >= need_base + Z16_B) ? (f16*)(ws + need_base) : nullptr;

    prep_all<<<dim3(2048), dim3(256), 0, stream>>>(
        x, h, wz, uz, wr, ur, wh, uh, x16, h16, B1, B2);
    gru_gemm16p<1><<<dim3((M_ROWS / BM) * 8), dim3(512), 0, stream>>>(
        x16, h16, h16, B1, bz, br, out, rh, z16);
    gru_gemm16p<2><<<dim3((M_ROWS / BM) * 4), dim3(512), 0, stream>>>(
        x16, rh, h16, B2, bh, nullptr, out, nullptr, z16);
  } else {
    build_wcat<<<dim3((wtot + 255) / 256), dim3(256), 0, stream>>>(wz, uz, wr, ur, wh, uh, B1, B2);
    gru_gemm_fb<1><<<dim3((M_ROWS / 128) * 8), dim3(256), 0, stream>>>(x, h, B1, nullptr, bz, br, out, rh);
    gru_gemm_fb<2><<<dim3((M_ROWS / 128) * 4), dim3(256), 0, stream>>>(x, h, B2, rh, bh, nullptr, out, rh);
  }
}